// Round 5
// baseline (578.307 us; speedup 1.0000x reference)
//
#include <hip/hip_runtime.h>
#include <cstdint>

// ---------------------------------------------------------------------------
// FP8 QDQ Conv2d:  out = conv2d(qdq_fp8(x,2), w*2, pad=1) + bias
//                = 4 * conv2d(fp8(x/2), fp8(w)) + bias     (exact in fp8)
// x: (32,128,56,56) f32 NCHW; w: (256,128,3,3) f32 (fp8-representable); b: (256,)
// out: (32,256,56,56) f32.  Implicit GEMM: M = 100352, N = 256, K = 9*128.
//
// R5 = R1's proven schedule/geometry EXACTLY (128x128 tile, 256 thr, 2x2
// waves, stage->sync->compute->sync per rs, zero-page halo), with the inner
// loop upgraded to MX-scaled fp8 MFMA (16x16x128, unit scales 0x7F = 2^0):
// 2x MFMA pipe rate, one MFMA per fragment pair per rs. (m145->m148 ladder:
// +64% on this same structure.)
// ---------------------------------------------------------------------------

#define NB   32
#define CIN  128
#define HW   56
#define KOUT 256
#define MTOT (32 * 56 * 56)                      // 100352

#define ACT_BYTES (32u * 56u * 56u * 128u)       // 12,845,056  NHWC fp8
#define WT_OFF    ACT_BYTES
#define WT_BYTES  (9u * 256u * 128u)             // 294,912     [rs][k][c] fp8
#define ZP_OFF    (WT_OFF + WT_BYTES)            // 128B zero page for halo rows

typedef float        f32x4 __attribute__((ext_vector_type(4)));
typedef unsigned int u32x4 __attribute__((ext_vector_type(4)));
typedef int          i32x8 __attribute__((ext_vector_type(8)));

union frag32 { u32x4 q[2]; i32x8 v; };

// --------------------------- fp8 pack helpers ------------------------------
__device__ __forceinline__ unsigned int pack2_fp8(float a, float b) {
  a = fminf(fmaxf(a, -448.f), 448.f);
  b = fminf(fmaxf(b, -448.f), 448.f);
  // v_cvt_pk_fp8_f32: RNE, saturating, OCP e4m3fn on gfx950. byte0=a, byte1=b.
  return (unsigned int)__builtin_amdgcn_cvt_pk_fp8_f32(a, b, 0, false);
}

// ------------------- kernel 1: qdq + NCHW -> NHWC fp8 ----------------------
__global__ __launch_bounds__(256) void qdq_pack(const float* __restrict__ X,
                                                unsigned char* __restrict__ act) {
  const int nh = blockIdx.x;               // 0..1791
  const int n = nh / HW, h = nh - n * HW;
  const float* xb = X + (size_t)n * (CIN * HW * HW) + h * HW;  // + c*3136 + w
  unsigned char* ob = act + (size_t)nh * (HW * CIN);

  for (int i = 0; i < 2; ++i) {
    int item = threadIdx.x + i * 256;
    if (item >= HW * 8) break;             // 56 w * 8 c-groups of 16
    int w = item % HW, cg = item / HW;
    unsigned int dw[4];
#pragma unroll
    for (int jj = 0; jj < 4; ++jj) {
      int c0 = cg * 16 + jj * 4;
      float v0 = xb[(c0 + 0) * 3136 + w] * 0.5f;
      float v1 = xb[(c0 + 1) * 3136 + w] * 0.5f;
      float v2 = xb[(c0 + 2) * 3136 + w] * 0.5f;
      float v3 = xb[(c0 + 3) * 3136 + w] * 0.5f;
      unsigned int lo = pack2_fp8(v0, v1) & 0xffffu;
      unsigned int hi = pack2_fp8(v2, v3) & 0xffffu;
      dw[jj] = lo | (hi << 16);
    }
    u32x4 v = {dw[0], dw[1], dw[2], dw[3]};
    *(u32x4*)(ob + w * CIN + cg * 16) = v;
  }
}

// --------------- kernel 2: weight OIHW f32 -> [rs][k][c] fp8 ---------------
__global__ __launch_bounds__(256) void pack_weight(const float* __restrict__ W,
                                                   unsigned char* __restrict__ wt,
                                                   unsigned int* __restrict__ zp) {
  if (blockIdx.x == 0 && threadIdx.x < 32) zp[threadIdx.x] = 0u;
  int gid = blockIdx.x * 256 + threadIdx.x;   // one dword (4 c) per thread
  int o = gid * 4;
  if (o >= (int)WT_BYTES) return;
  int rs = o >> 15;                // /32768 (= 256*128)
  int rem = o & 32767;
  int k  = rem >> 7;
  int c0 = rem & 127;
  // W[k][c][r][s] at k*1152 + c*9 + rs
  float v0 = W[k * 1152 + (c0 + 0) * 9 + rs];
  float v1 = W[k * 1152 + (c0 + 1) * 9 + rs];
  float v2 = W[k * 1152 + (c0 + 2) * 9 + rs];
  float v3 = W[k * 1152 + (c0 + 3) * 9 + rs];
  unsigned int dw = (pack2_fp8(v0, v1) & 0xffffu) | (pack2_fp8(v2, v3) << 16);
  *(unsigned int*)(wt + o) = dw;
}

// ------------------------- kernel 3: implicit GEMM -------------------------
__device__ __forceinline__ void g2l16(const void* g, void* l) {
  __builtin_amdgcn_global_load_lds((const __attribute__((address_space(1))) void*)g,
                                   (__attribute__((address_space(3))) void*)l,
                                   16, 0, 0);
}

__global__ __launch_bounds__(256, 4) void conv_mfma(const unsigned char* __restrict__ act,
                                                    const unsigned char* __restrict__ wt,
                                                    const unsigned char* __restrict__ zp,
                                                    const float* __restrict__ bias,
                                                    float* __restrict__ out) {
  __shared__ __align__(16) unsigned char ldsA[16384];   // [128 m][128 c]
  __shared__ __align__(16) unsigned char ldsB[16384];   // [128 k][128 c]
  const int tid  = threadIdx.x;
  const int lane = tid & 63;
  const int wid  = tid >> 6;
  const int wr   = wid >> 1, wc = wid & 1;            // 2x2 waves -> 64x64 each
  const int bm   = blockIdx.x << 7;                   // 784 m-tiles
  const int bn   = blockIdx.y << 7;                   // 2 k-tiles

  // staging geometry: 8 threads x 16B per 128B row; 32 rows/round, 4 rounds
  const int srow   = tid >> 3;                        // 0..31
  const int sphys  = (tid & 7) << 4;                  // linear LDS dest chunk
  const int schunk = ((tid & 7) ^ (srow & 7)) << 4;   // XOR-swizzled global src chunk

  int an_[4], ah_[4], aw_[4];
#pragma unroll
  for (int q = 0; q < 4; ++q) {
    int m = bm + srow + 32 * q;
    int n = m / 3136;
    int hw = m - n * 3136;
    int h = hw / 56;
    an_[q] = n; ah_[q] = h; aw_[q] = hw - h * 56;
  }

  const f32x4 zero = {0.f, 0.f, 0.f, 0.f};
  f32x4 acc[4][4];
#pragma unroll
  for (int i = 0; i < 4; ++i)
#pragma unroll
    for (int j = 0; j < 4; ++j) acc[i][j] = zero;

  // MX fragment read geometry: lane holds K-bytes [kc*32, kc*32+32) of its row.
  const int kc2 = (lane >> 4) << 1;        // chunk16 index pair base (0,2,4,6)

  for (int rs = 0; rs < 9; ++rs) {
    const int r = rs / 3, s = rs - 3 * (rs / 3);
    const unsigned char* wseg = wt + rs * (KOUT * CIN);

    // stage A tile: 128 rows x 128B (halo rows -> zero page)
#pragma unroll
    for (int q = 0; q < 4; ++q) {
      int hi = ah_[q] + r - 1;
      int wi = aw_[q] + s - 1;
      bool ok = ((unsigned)hi < 56u) && ((unsigned)wi < 56u);
      const unsigned char* src =
          ok ? act + (((an_[q] * 56 + hi) * 56 + wi) << 7) + schunk : zp + schunk;
      g2l16(src, &ldsA[((srow + 32 * q) << 7) + sphys]);
    }
    // stage B tile: 128 k-rows x 128B of c
#pragma unroll
    for (int q = 0; q < 4; ++q) {
      int kl = srow + 32 * q;
      g2l16(wseg + ((bn + kl) << 7) + schunk, &ldsB[(kl << 7) + sphys]);
    }
    __syncthreads();

    // ---- one scaled MFMA (K=128) per fragment pair ----
    frag32 bv[4];
#pragma unroll
    for (int ni = 0; ni < 4; ++ni) {
      int col = (wc << 6) + (ni << 4) + (lane & 15);
      int x = col & 7;
      bv[ni].q[0] = *(const u32x4*)(&ldsB[(col << 7) + ((kc2 ^ x) << 4)]);
      bv[ni].q[1] = *(const u32x4*)(&ldsB[(col << 7) + (((kc2 + 1) ^ x) << 4)]);
    }
#pragma unroll
    for (int mi = 0; mi < 4; ++mi) {
      int row = (wr << 6) + (mi << 4) + (lane & 15);
      int x = row & 7;
      frag32 av;
      av.q[0] = *(const u32x4*)(&ldsA[(row << 7) + ((kc2 ^ x) << 4)]);
      av.q[1] = *(const u32x4*)(&ldsA[(row << 7) + (((kc2 + 1) ^ x) << 4)]);
#pragma unroll
      for (int ni = 0; ni < 4; ++ni)
        acc[mi][ni] = __builtin_amdgcn_mfma_scale_f32_16x16x128_f8f6f4(
            av.v, bv[ni].v, acc[mi][ni], 0 /*A fmt: fp8 e4m3*/,
            0 /*B fmt: fp8 e4m3*/, 0, 0x7f7f7f7f /*A scales = 1.0*/,
            0, 0x7f7f7f7f /*B scales = 1.0*/);
    }
    __syncthreads();
  }

  // epilogue: out[n][k][hw] = 4*acc + bias[k]; 4 consecutive m per lane = float4
#pragma unroll
  for (int ni = 0; ni < 4; ++ni) {
    int k = bn + (wc << 6) + (ni << 4) + (lane & 15);
    float bvv = bias[k];
#pragma unroll
    for (int mi = 0; mi < 4; ++mi) {
      int m = bm + (wr << 6) + (mi << 4) + ((lane >> 4) << 2);
      int n = m / 3136;
      int hw = m - n * 3136;
      f32x4 v = acc[mi][ni];
      v = v * 4.0f + bvv;
      *(f32x4*)(out + (size_t)(n * KOUT + k) * 3136 + hw) = v;
    }
  }
}

// ---------------------------------------------------------------------------
extern "C" void kernel_launch(void* const* d_in, const int* in_sizes, int n_in,
                              void* d_out, int out_size, void* d_ws, size_t ws_size,
                              hipStream_t stream) {
  const float* X = (const float*)d_in[0];
  const float* W = (const float*)d_in[1];
  const float* B = (const float*)d_in[2];
  float* out = (float*)d_out;

  unsigned char* act = (unsigned char*)d_ws;
  unsigned char* wtb = act + WT_OFF;
  unsigned char* zp  = act + ZP_OFF;

  hipLaunchKernelGGL(qdq_pack,    dim3(NB * HW), dim3(256), 0, stream, X, act);
  hipLaunchKernelGGL(pack_weight, dim3(288),     dim3(256), 0, stream, W, wtb,
                     (unsigned int*)zp);
  hipLaunchKernelGGL(conv_mfma,   dim3(784, 2),  dim3(256), 0, stream, act, wtb, zp, B,
                     out);
}

// Round 6
// 105.994 us; speedup vs baseline: 5.4561x; 5.4561x over previous
//
#include <hip/hip_runtime.h>
#include <cstdint>

// ---------------------------------------------------------------------------
// FP8 QDQ Conv2d:  out = conv2d(qdq_fp8(x,2), w*2, pad=1) + bias
//                = 4 * conv2d(fp8(x/2), fp8(w)) + bias     (exact in fp8)
// x: (32,128,56,56) f32 NCHW; w: (256,128,3,3) f32 (fp8-representable); b: (256,)
// out: (32,256,56,56) f32.  Implicit GEMM: M = 100352, N = 256, K = 9*128.
//
// R6 = R5 (R1 schedule + MX-scaled 16x16x128 fp8 MFMA, unit scales) with the
// spill fixed: no launch_bounds min-wave cap (R5's cap -> VGPR 64 -> scratch
// explosion, FETCH 761MB/WRITE 1.2GB), no union type-pun (shufflevector
// keeps fragments in registers). Math identical to R5 (passed, absmax 2.0).
// ---------------------------------------------------------------------------

#define NB   32
#define CIN  128
#define HW   56
#define KOUT 256
#define MTOT (32 * 56 * 56)                      // 100352

#define ACT_BYTES (32u * 56u * 56u * 128u)       // 12,845,056  NHWC fp8
#define WT_OFF    ACT_BYTES
#define WT_BYTES  (9u * 256u * 128u)             // 294,912     [rs][k][c] fp8
#define ZP_OFF    (WT_OFF + WT_BYTES)            // 128B zero page for halo rows

typedef float        f32x4 __attribute__((ext_vector_type(4)));
typedef unsigned int u32x4 __attribute__((ext_vector_type(4)));
typedef int          i32x4 __attribute__((ext_vector_type(4)));
typedef int          i32x8 __attribute__((ext_vector_type(8)));

// --------------------------- fp8 pack helpers ------------------------------
__device__ __forceinline__ unsigned int pack2_fp8(float a, float b) {
  a = fminf(fmaxf(a, -448.f), 448.f);
  b = fminf(fmaxf(b, -448.f), 448.f);
  // v_cvt_pk_fp8_f32: RNE, saturating, OCP e4m3fn on gfx950. byte0=a, byte1=b.
  return (unsigned int)__builtin_amdgcn_cvt_pk_fp8_f32(a, b, 0, false);
}

// ------------------- kernel 1: qdq + NCHW -> NHWC fp8 ----------------------
__global__ __launch_bounds__(256) void qdq_pack(const float* __restrict__ X,
                                                unsigned char* __restrict__ act) {
  const int nh = blockIdx.x;               // 0..1791
  const int n = nh / HW, h = nh - n * HW;
  const float* xb = X + (size_t)n * (CIN * HW * HW) + h * HW;  // + c*3136 + w
  unsigned char* ob = act + (size_t)nh * (HW * CIN);

  for (int i = 0; i < 2; ++i) {
    int item = threadIdx.x + i * 256;
    if (item >= HW * 8) break;             // 56 w * 8 c-groups of 16
    int w = item % HW, cg = item / HW;
    unsigned int dw[4];
#pragma unroll
    for (int jj = 0; jj < 4; ++jj) {
      int c0 = cg * 16 + jj * 4;
      float v0 = xb[(c0 + 0) * 3136 + w] * 0.5f;
      float v1 = xb[(c0 + 1) * 3136 + w] * 0.5f;
      float v2 = xb[(c0 + 2) * 3136 + w] * 0.5f;
      float v3 = xb[(c0 + 3) * 3136 + w] * 0.5f;
      unsigned int lo = pack2_fp8(v0, v1) & 0xffffu;
      unsigned int hi = pack2_fp8(v2, v3) & 0xffffu;
      dw[jj] = lo | (hi << 16);
    }
    u32x4 v = {dw[0], dw[1], dw[2], dw[3]};
    *(u32x4*)(ob + w * CIN + cg * 16) = v;
  }
}

// --------------- kernel 2: weight OIHW f32 -> [rs][k][c] fp8 ---------------
__global__ __launch_bounds__(256) void pack_weight(const float* __restrict__ W,
                                                   unsigned char* __restrict__ wt,
                                                   unsigned int* __restrict__ zp) {
  if (blockIdx.x == 0 && threadIdx.x < 32) zp[threadIdx.x] = 0u;
  int gid = blockIdx.x * 256 + threadIdx.x;   // one dword (4 c) per thread
  int o = gid * 4;
  if (o >= (int)WT_BYTES) return;
  int rs = o >> 15;                // /32768 (= 256*128)
  int rem = o & 32767;
  int k  = rem >> 7;
  int c0 = rem & 127;
  // W[k][c][r][s] at k*1152 + c*9 + rs
  float v0 = W[k * 1152 + (c0 + 0) * 9 + rs];
  float v1 = W[k * 1152 + (c0 + 1) * 9 + rs];
  float v2 = W[k * 1152 + (c0 + 2) * 9 + rs];
  float v3 = W[k * 1152 + (c0 + 3) * 9 + rs];
  unsigned int dw = (pack2_fp8(v0, v1) & 0xffffu) | (pack2_fp8(v2, v3) << 16);
  *(unsigned int*)(wt + o) = dw;
}

// ------------------------- kernel 3: implicit GEMM -------------------------
__device__ __forceinline__ void g2l16(const void* g, void* l) {
  __builtin_amdgcn_global_load_lds((const __attribute__((address_space(1))) void*)g,
                                   (__attribute__((address_space(3))) void*)l,
                                   16, 0, 0);
}

__device__ __forceinline__ i32x8 ld_frag(const unsigned char* base, int row, int kc2) {
  const int x = row & 7;
  i32x4 lo = *(const i32x4*)(base + (row << 7) + ((kc2 ^ x) << 4));
  i32x4 hi = *(const i32x4*)(base + (row << 7) + (((kc2 + 1) ^ x) << 4));
  return __builtin_shufflevector(lo, hi, 0, 1, 2, 3, 4, 5, 6, 7);
}

__global__ __launch_bounds__(256) void conv_mfma(const unsigned char* __restrict__ act,
                                                 const unsigned char* __restrict__ wt,
                                                 const unsigned char* __restrict__ zp,
                                                 const float* __restrict__ bias,
                                                 float* __restrict__ out) {
  __shared__ __align__(16) unsigned char ldsA[16384];   // [128 m][128 c]
  __shared__ __align__(16) unsigned char ldsB[16384];   // [128 k][128 c]
  const int tid  = threadIdx.x;
  const int lane = tid & 63;
  const int wid  = tid >> 6;
  const int wr   = wid >> 1, wc = wid & 1;            // 2x2 waves -> 64x64 each
  const int bm   = blockIdx.x << 7;                   // 784 m-tiles
  const int bn   = blockIdx.y << 7;                   // 2 k-tiles

  // staging geometry: 8 threads x 16B per 128B row; 32 rows/round, 4 rounds
  const int srow   = tid >> 3;                        // 0..31
  const int sphys  = (tid & 7) << 4;                  // linear LDS dest chunk
  const int schunk = ((tid & 7) ^ (srow & 7)) << 4;   // XOR-swizzled global src chunk

  int an_[4], ah_[4], aw_[4];
#pragma unroll
  for (int q = 0; q < 4; ++q) {
    int m = bm + srow + 32 * q;
    int n = m / 3136;
    int hw = m - n * 3136;
    int h = hw / 56;
    an_[q] = n; ah_[q] = h; aw_[q] = hw - h * 56;
  }

  const f32x4 zero = {0.f, 0.f, 0.f, 0.f};
  f32x4 acc[4][4];
#pragma unroll
  for (int i = 0; i < 4; ++i)
#pragma unroll
    for (int j = 0; j < 4; ++j) acc[i][j] = zero;

  // MX fragment geometry: lane holds K-bytes [(lane>>4)*32, +32) of its row.
  const int kc2 = (lane >> 4) << 1;        // 16B-chunk index pair base (0,2,4,6)

  for (int rs = 0; rs < 9; ++rs) {
    const int r = rs / 3, s = rs - 3 * (rs / 3);
    const unsigned char* wseg = wt + rs * (KOUT * CIN);

    // stage A tile: 128 rows x 128B (halo rows -> zero page)
#pragma unroll
    for (int q = 0; q < 4; ++q) {
      int hi = ah_[q] + r - 1;
      int wi = aw_[q] + s - 1;
      bool ok = ((unsigned)hi < 56u) && ((unsigned)wi < 56u);
      const unsigned char* src =
          ok ? act + (((an_[q] * 56 + hi) * 56 + wi) << 7) + schunk : zp + schunk;
      g2l16(src, &ldsA[((srow + 32 * q) << 7) + sphys]);
    }
    // stage B tile: 128 k-rows x 128B of c
#pragma unroll
    for (int q = 0; q < 4; ++q) {
      int kl = srow + 32 * q;
      g2l16(wseg + ((bn + kl) << 7) + schunk, &ldsB[(kl << 7) + sphys]);
    }
    __syncthreads();

    // ---- one scaled MFMA (K=128) per fragment pair ----
    i32x8 bv0 = ld_frag(ldsB, (wc << 6) + (0 << 4) + (lane & 15), kc2);
    i32x8 bv1 = ld_frag(ldsB, (wc << 6) + (1 << 4) + (lane & 15), kc2);
    i32x8 bv2 = ld_frag(ldsB, (wc << 6) + (2 << 4) + (lane & 15), kc2);
    i32x8 bv3 = ld_frag(ldsB, (wc << 6) + (3 << 4) + (lane & 15), kc2);
#pragma unroll
    for (int mi = 0; mi < 4; ++mi) {
      i32x8 av = ld_frag(ldsA, (wr << 6) + (mi << 4) + (lane & 15), kc2);
      acc[mi][0] = __builtin_amdgcn_mfma_scale_f32_16x16x128_f8f6f4(
          av, bv0, acc[mi][0], 0, 0, 0, 0x7f7f7f7f, 0, 0x7f7f7f7f);
      acc[mi][1] = __builtin_amdgcn_mfma_scale_f32_16x16x128_f8f6f4(
          av, bv1, acc[mi][1], 0, 0, 0, 0x7f7f7f7f, 0, 0x7f7f7f7f);
      acc[mi][2] = __builtin_amdgcn_mfma_scale_f32_16x16x128_f8f6f4(
          av, bv2, acc[mi][2], 0, 0, 0, 0x7f7f7f7f, 0, 0x7f7f7f7f);
      acc[mi][3] = __builtin_amdgcn_mfma_scale_f32_16x16x128_f8f6f4(
          av, bv3, acc[mi][3], 0, 0, 0, 0x7f7f7f7f, 0, 0x7f7f7f7f);
    }
    __syncthreads();
  }

  // epilogue: out[n][k][hw] = 4*acc + bias[k]; 4 consecutive m per lane = float4
#pragma unroll
  for (int ni = 0; ni < 4; ++ni) {
    int k = bn + (wc << 6) + (ni << 4) + (lane & 15);
    float bvv = bias[k];
#pragma unroll
    for (int mi = 0; mi < 4; ++mi) {
      int m = bm + (wr << 6) + (mi << 4) + ((lane >> 4) << 2);
      int n = m / 3136;
      int hw = m - n * 3136;
      f32x4 v = acc[mi][ni];
      v = v * 4.0f + bvv;
      *(f32x4*)(out + (size_t)(n * KOUT + k) * 3136 + hw) = v;
    }
  }
}

// ---------------------------------------------------------------------------
extern "C" void kernel_launch(void* const* d_in, const int* in_sizes, int n_in,
                              void* d_out, int out_size, void* d_ws, size_t ws_size,
                              hipStream_t stream) {
  const float* X = (const float*)d_in[0];
  const float* W = (const float*)d_in[1];
  const float* B = (const float*)d_in[2];
  float* out = (float*)d_out;

  unsigned char* act = (unsigned char*)d_ws;
  unsigned char* wtb = act + WT_OFF;
  unsigned char* zp  = act + ZP_OFF;

  hipLaunchKernelGGL(qdq_pack,    dim3(NB * HW), dim3(256), 0, stream, X, act);
  hipLaunchKernelGGL(pack_weight, dim3(288),     dim3(256), 0, stream, W, wtb,
                     (unsigned int*)zp);
  hipLaunchKernelGGL(conv_mfma,   dim3(784, 2),  dim3(256), 0, stream, act, wtb, zp, B,
                     out);
}